// Round 3
// baseline (88336.060 us; speedup 1.0000x reference)
//
#include <hip/hip_runtime.h>
#include <hip/hip_cooperative_groups.h>

namespace cg = cooperative_groups;

#define TT 256      // timesteps
#define GRID 256
#define BDIM 256

typedef unsigned short u16;
typedef unsigned int u32;
typedef __attribute__((ext_vector_type(8))) short bf16x8;
typedef __attribute__((ext_vector_type(4))) float f32x4;

struct P {
  const float* obs; const float* action; const int* is_first;
  const float* w_prior_in; const float* g_prior_in; const float* bb_prior_in;
  const float* w_gru; const float* g_gru; const float* bb_gru;
  const float* w_prior_out; const float* g_prior_out; const float* bb_prior_out;
  const float* w_prior_stats; const float* b_prior_stats;
  const float* w_post; const float* g_post; const float* bb_post;
  const float* w_post_stats; const float* b_post_stats;
  const float* initial_deter;
  float* out;
  // split-bf16 weights, N-major, K-planes [hi | hi | lo]
  u16 *WgT3;    // [1536][3072]  (w_gru, K=1024)
  u16 *W2T3;    // [1024][1632]  (n<512: prior_out K=[deter512|pad32]; n>=512: post K=[deter512|obs18pad14])
  u16 *WsT3;    // [128][3072]   (n<64: prior_stats on h2[0:512]; n>=64: post_stats on h2[512:1024])
  float *deter0, *init_mean;
  float *deter;   // [256][512] fp32 state
  float *stoch;   // [256][32]  fp32 state (posterior mean)
  u16 *xg;        // [256][3072] A-planes [hi|lo|hi] of [h(512)|deter(512)]
  float *gates;   // [256][1536] fp32
  u16 *dox;       // [256][1632] A-planes [hi|lo|hi] of [deter(512)|obs(18)pad(14)]
  float *hraw;    // [256][1024] fp32
  u16 *h2;        // [256][3072] A-planes [hi|lo|hi] of silu(ln(hraw)) halves
};

__device__ __forceinline__ float b2f(u16 u) {
  union { float f; u32 i; } v; v.i = ((u32)u) << 16; return v.f;
}
__device__ __forceinline__ u16 f2b(float f) {
  union { float f; u32 i; } v; v.f = f;
  u32 r = v.i + 0x7FFF + ((v.i >> 16) & 1);   // RNE
  return (u16)(r >> 16);
}
__device__ __forceinline__ float sigm(float x) { return 1.f / (1.f + __expf(-x)); }
__device__ __forceinline__ float splus(float x) { return x > 15.f ? x : log1pf(__expf(x)); }

// ---- prior_in head (fp32 VALU): h = silu(ln(x @ Wpi)); writes xg h-planes for row b ----
__device__ __forceinline__ void h_from_x(const P& p, int b, float xv, int lane) {
  float a0[8];
  #pragma unroll
  for (int c = 0; c < 8; ++c) a0[c] = 0.f;
  #pragma unroll 4
  for (int j = 0; j < 36; ++j) {
    float s = __shfl(xv, j, 64);
    const float* wr = p.w_prior_in + j * 512 + lane;
    #pragma unroll
    for (int c = 0; c < 8; ++c) a0[c] = fmaf(s, wr[c << 6], a0[c]);
  }
  float sm = 0.f, sq = 0.f;
  #pragma unroll
  for (int c = 0; c < 8; ++c) { sm += a0[c]; sq += a0[c] * a0[c]; }
  #pragma unroll
  for (int o = 32; o; o >>= 1) { sm += __shfl_xor(sm, o); sq += __shfl_xor(sq, o); }
  float m = sm * (1.f / 512.f);
  float rs = rsqrtf(sq * (1.f / 512.f) - m * m + 1e-3f);
  size_t rowb = (size_t)b * 3072;
  #pragma unroll
  for (int c = 0; c < 8; ++c) {
    int col = lane + (c << 6);
    float v = (a0[c] - m) * rs * p.g_prior_in[col] + p.bb_prior_in[col];
    v = v * sigm(v);
    u16 hi = f2b(v); u16 lo = f2b(v - b2f(hi));
    p.xg[rowb + col] = hi;
    p.xg[rowb + 1024 + col] = lo;
    p.xg[rowb + 2048 + col] = hi;
  }
}

// ================= prep kernels =================
__global__ void k_weights(P p) {
  const int E1 = 1536 * 1024, E2 = 1024 * 544, E3 = 128 * 1024;
  const int total = E1 + E2 + E3;
  for (int idx = blockIdx.x * blockDim.x + threadIdx.x; idx < total;
       idx += gridDim.x * blockDim.x) {
    float w; u16* dst; int kk, kappa;
    if (idx < E1) {
      int n = idx >> 10; kk = idx & 1023; kappa = 1024;
      w = p.w_gru[kk * 1536 + n];
      dst = p.WgT3 + (size_t)n * 3072;
    } else if (idx < E1 + E2) {
      int t = idx - E1; int n = t / 544; kk = t - n * 544; kappa = 544;
      if (n < 512) w = (kk < 512) ? p.w_prior_out[kk * 512 + n] : 0.f;
      else         w = (kk < 530) ? p.w_post[kk * 512 + (n - 512)] : 0.f;
      dst = p.W2T3 + (size_t)n * 1632;
    } else {
      int t = idx - E1 - E2; int n = t >> 10; kk = t & 1023; kappa = 1024;
      if (n < 64) w = (kk < 512) ? p.w_prior_stats[kk * 64 + n] : 0.f;
      else        w = (kk >= 512) ? p.w_post_stats[(kk - 512) * 64 + (n - 64)] : 0.f;
      dst = p.WsT3 + (size_t)n * 3072;
    }
    u16 hi = f2b(w); u16 lo = f2b(w - b2f(hi));
    dst[kk] = hi; dst[kappa + kk] = hi; dst[2 * kappa + kk] = lo;
  }
}

__global__ void k_init_state(P p) {
  __shared__ float d0s[512], tmp[512], red[256];
  int tid = threadIdx.x;
  for (int n = tid; n < 512; n += 256) { d0s[n] = tanhf(p.initial_deter[n]); p.deter0[n] = d0s[n]; }
  __syncthreads();
  for (int n = tid; n < 512; n += 256) {
    float s = 0.f;
    for (int d = 0; d < 512; ++d) s = fmaf(d0s[d], p.w_prior_out[d * 512 + n], s);
    tmp[n] = s;
  }
  __syncthreads();
  float ls = 0.f, lq = 0.f;
  for (int n = tid; n < 512; n += 256) { ls += tmp[n]; lq += tmp[n] * tmp[n]; }
  red[tid] = ls; __syncthreads();
  for (int s = 128; s; s >>= 1) { if (tid < s) red[tid] += red[tid + s]; __syncthreads(); }
  float m = red[0] * (1.f / 512.f); __syncthreads();
  red[tid] = lq; __syncthreads();
  for (int s = 128; s; s >>= 1) { if (tid < s) red[tid] += red[tid + s]; __syncthreads(); }
  float rs = rsqrtf(red[0] * (1.f / 512.f) - m * m + 1e-3f); __syncthreads();
  for (int n = tid; n < 512; n += 256) {
    float h = (tmp[n] - m) * rs * p.g_prior_out[n] + p.bb_prior_out[n];
    tmp[n] = h * sigm(h);
  }
  __syncthreads();
  if (tid < 32) {
    float s = 0.f;
    for (int d = 0; d < 512; ++d) s = fmaf(tmp[d], p.w_prior_stats[d * 64 + tid], s);
    p.init_mean[tid] = s + p.b_prior_stats[tid];
  }
}

// ---- generic 128x128-tile split-bf16 GEMM: C = A3 @ B3^T (fp32 out) ----
__device__ void gemm_tiles(const u16* A, int lda, const u16* B, int ldb,
                           float* C, int ldc, int M, int ntn, int K3,
                           u16* Ab, u16* Bb, int bid, int nb, int tid) {
  const int wave = tid >> 6, lane = tid & 63, quad = lane >> 4, l15 = lane & 15;
  const int wr = (wave & 1) << 6, wc = (wave >> 1) << 6;
  const int ntm = (M + 127) >> 7;
  const int njobs = ntm * ntn;
  for (int j = bid; j < njobs; j += nb) {
    int tm = j / ntn, tn = j - tm * ntn;
    int r0 = tm << 7, c0 = tn << 7;
    f32x4 acc[4][4];
    #pragma unroll
    for (int a = 0; a < 4; ++a)
      #pragma unroll
      for (int bq = 0; bq < 4; ++bq) acc[a][bq] = f32x4{0.f, 0.f, 0.f, 0.f};
    for (int k0 = 0; k0 < K3; k0 += 32) {
      __syncthreads();
      #pragma unroll
      for (int s = 0; s < 2; ++s) {
        int ch = tid + (s << 8);
        int row = ch >> 2, ko = (ch & 3) << 3;
        *(uint4*)&Ab[(row << 5) + ko] =
            *(const uint4*)(A + (size_t)(r0 + row) * lda + k0 + ko);
        *(uint4*)&Bb[(row << 5) + ko] =
            *(const uint4*)(B + (size_t)(c0 + row) * ldb + k0 + ko);
      }
      __syncthreads();
      bf16x8 af[4], bf[4];
      #pragma unroll
      for (int s2 = 0; s2 < 4; ++s2) {
        af[s2] = *(const bf16x8*)&Ab[((wr + (s2 << 4) + l15) << 5) + (quad << 3)];
        bf[s2] = *(const bf16x8*)&Bb[((wc + (s2 << 4) + l15) << 5) + (quad << 3)];
      }
      #pragma unroll
      for (int mi = 0; mi < 4; ++mi)
        #pragma unroll
        for (int ni = 0; ni < 4; ++ni)
          acc[mi][ni] = __builtin_amdgcn_mfma_f32_16x16x32_bf16(af[mi], bf[ni], acc[mi][ni], 0, 0, 0);
    }
    #pragma unroll
    for (int mi = 0; mi < 4; ++mi)
      #pragma unroll
      for (int ni = 0; ni < 4; ++ni)
        #pragma unroll
        for (int r = 0; r < 4; ++r)
          C[(size_t)(r0 + wr + (mi << 4) + (quad << 2) + r) * ldc
            + c0 + wc + (ni << 4) + l15] = acc[mi][ni][r];
  }
}

// ================= main cooperative kernel: sequential over T =================
__global__ void __launch_bounds__(BDIM, 2) k_main(P p) {
  cg::grid_group grid = cg::this_grid();
  __shared__ u16 Ab[128 * 32], Bb[128 * 32];
  const int tid = threadIdx.x;
  const int bid = blockIdx.x, nb = gridDim.x;
  const int wave = tid >> 6, lane = tid & 63, quad = lane >> 4, l15 = lane & 15;
  const int gw = (bid << 2) + wave, nwv = nb << 2;

  for (int t = 0; t < TT; ++t) {
    // ---- A: per-row carry/reset + prior_in head ----
    for (int b = gw; b < 256; b += nwv) {
      int f = p.is_first[b * TT + t];
      bool rst0 = (f > 0);
      bool rst = rst0 || (t == 0);
      if (rst) {
        size_t rowb = (size_t)b * 3072;
        #pragma unroll
        for (int c = 0; c < 8; ++c) {
          int d = lane + (c << 6);
          float v = p.deter0[d];
          p.deter[(size_t)b * 512 + d] = v;
          u16 hi = f2b(v); u16 lo = f2b(v - b2f(hi));
          p.xg[rowb + 512 + d] = hi;
          p.xg[rowb + 1536 + d] = lo;
          p.xg[rowb + 2560 + d] = hi;
        }
      }
      float xv = 0.f;
      if (lane < 32) xv = rst ? p.init_mean[lane] : p.stoch[b * 32 + lane];
      else if (lane < 36) xv = rst0 ? 0.f : p.action[((size_t)b * TT + t) * 4 + (lane - 32)];
      h_from_x(p, b, xv, lane);
    }
    grid.sync();

    // ---- B: gates = xg3 @ WgT3  (256 x 1536, K3=3072) ----
    gemm_tiles(p.xg, 3072, p.WgT3, 3072, p.gates, 1536, 256, 12, 3072,
               Ab, Bb, bid, nb, tid);
    grid.sync();

    // ---- C: LN(gates) -> GRU update -> deter', out-deter, xg/dox refresh ----
    for (int b = gw; b < 256; b += nwv) {
      const float* grow = p.gates + (size_t)b * 1536;
      float g[24];
      float sm = 0.f, sq = 0.f;
      #pragma unroll
      for (int c = 0; c < 24; ++c) {
        g[c] = grow[lane + (c << 6)];
        sm += g[c]; sq += g[c] * g[c];
      }
      #pragma unroll
      for (int o = 32; o; o >>= 1) { sm += __shfl_xor(sm, o); sq += __shfl_xor(sq, o); }
      float m = sm * (1.f / 1536.f);
      float rs = rsqrtf(sq * (1.f / 1536.f) - m * m + 1e-3f);
      float* orow = p.out + ((size_t)b * TT + t) * 1216;
      size_t rowx = (size_t)b * 3072, rowd = (size_t)b * 1632;
      #pragma unroll
      for (int c = 0; c < 8; ++c) {
        int d = lane + (c << 6);
        float gr = (g[c]      - m) * rs * p.g_gru[d]        + p.bb_gru[d];
        float gc = (g[c + 8]  - m) * rs * p.g_gru[512 + d]  + p.bb_gru[512 + d];
        float gu = (g[c + 16] - m) * rs * p.g_gru[1024 + d] + p.bb_gru[1024 + d];
        float r_ = sigm(gr);
        float u_ = sigm(gu - 1.0f);
        float rc = r_ * gc;
        float cand = rc * sigm(rc);
        float dp = p.deter[(size_t)b * 512 + d];
        float dn = u_ * cand + (1.f - u_) * dp;
        p.deter[(size_t)b * 512 + d] = dn;
        orow[d] = dn; orow[608 + d] = dn;
        u16 hi = f2b(dn); u16 lo = f2b(dn - b2f(hi));
        p.xg[rowx + 512 + d] = hi;
        p.xg[rowx + 1536 + d] = lo;
        p.xg[rowx + 2560 + d] = hi;
        p.dox[rowd + d] = hi;
        p.dox[rowd + 544 + d] = lo;
        p.dox[rowd + 1088 + d] = hi;
      }
      if (lane < 32) {
        float ov = (lane < 18) ? p.obs[((size_t)b * TT + t) * 18 + lane] : 0.f;
        u16 hi = f2b(ov); u16 lo = f2b(ov - b2f(hi));
        p.dox[rowd + 512 + lane] = hi;
        p.dox[rowd + 1056 + lane] = lo;
        p.dox[rowd + 1600 + lane] = hi;
      }
    }
    grid.sync();

    // ---- D: hraw = dox3 @ W2T3  (256 x 1024, K3=1632) ----
    gemm_tiles(p.dox, 1632, p.W2T3, 1632, p.hraw, 1024, 256, 8, 1632,
               Ab, Bb, bid, nb, tid);
    grid.sync();

    // ---- E: two LNs + silu -> h2 planes ----
    for (int b = gw; b < 256; b += nwv) {
      size_t rowh = (size_t)b * 3072;
      #pragma unroll
      for (int hh = 0; hh < 2; ++hh) {
        const float* hb = p.hraw + (size_t)b * 1024 + (hh << 9);
        const float* gv = hh ? p.g_post : p.g_prior_out;
        const float* bv = hh ? p.bb_post : p.bb_prior_out;
        float v[8];
        float sm = 0.f, sq = 0.f;
        #pragma unroll
        for (int c = 0; c < 8; ++c) {
          v[c] = hb[lane + (c << 6)];
          sm += v[c]; sq += v[c] * v[c];
        }
        #pragma unroll
        for (int o = 32; o; o >>= 1) { sm += __shfl_xor(sm, o); sq += __shfl_xor(sq, o); }
        float m = sm * (1.f / 512.f);
        float rs = rsqrtf(sq * (1.f / 512.f) - m * m + 1e-3f);
        #pragma unroll
        for (int c = 0; c < 8; ++c) {
          int d = lane + (c << 6);
          float x = (v[c] - m) * rs * gv[d] + bv[d];
          x = x * sigm(x);
          int col = (hh << 9) + d;
          u16 hi = f2b(x); u16 lo = f2b(x - b2f(hi));
          p.h2[rowh + col] = hi;
          p.h2[rowh + 1024 + col] = lo;
          p.h2[rowh + 2048 + col] = hi;
        }
      }
    }
    grid.sync();

    // ---- F: stats = h2 @ WsT3 (32-row tiles, N=128, K3=3072) + epilogue ----
    {
      const int sr = (wave & 1) << 4, sc = (wave >> 1) << 6;
      for (int j = bid; j < 8; j += nb) {
        int r0 = j << 5;
        f32x4 acc[4];
        #pragma unroll
        for (int z = 0; z < 4; ++z) acc[z] = f32x4{0.f, 0.f, 0.f, 0.f};
        for (int k0 = 0; k0 < 3072; k0 += 32) {
          __syncthreads();
          if (tid < 128) {
            int row = tid >> 2, ko = (tid & 3) << 3;
            *(uint4*)&Ab[(row << 5) + ko] =
                *(const uint4*)(p.h2 + (size_t)(r0 + row) * 3072 + k0 + ko);
          }
          #pragma unroll
          for (int s = 0; s < 2; ++s) {
            int ch = tid + (s << 8);
            int row = ch >> 2, ko = (ch & 3) << 3;
            *(uint4*)&Bb[(row << 5) + ko] =
                *(const uint4*)(p.WsT3 + (size_t)row * 3072 + k0 + ko);
          }
          __syncthreads();
          bf16x8 af = *(const bf16x8*)&Ab[((sr + l15) << 5) + (quad << 3)];
          #pragma unroll
          for (int ns = 0; ns < 4; ++ns) {
            bf16x8 bf = *(const bf16x8*)&Bb[((sc + (ns << 4) + l15) << 5) + (quad << 3)];
            acc[ns] = __builtin_amdgcn_mfma_f32_16x16x32_bf16(af, bf, acc[ns], 0, 0, 0);
          }
        }
        #pragma unroll
        for (int ns = 0; ns < 4; ++ns)
          #pragma unroll
          for (int r = 0; r < 4; ++r) {
            int b = r0 + sr + (quad << 2) + r;
            int col = sc + (ns << 4) + l15;
            float v = acc[ns][r];
            float* orow = p.out + ((size_t)b * TT + t) * 1216;
            if (col < 32) {
              v += p.b_prior_stats[col];
              orow[1120 + col] = v; orow[1152 + col] = v;
            } else if (col < 64) {
              v = splus(v + p.b_prior_stats[col]) + 0.1f;
              orow[1184 + col - 32] = v;
            } else if (col < 96) {
              v += p.b_post_stats[col - 64];
              orow[512 + col - 64] = v; orow[544 + col - 64] = v;
              p.stoch[b * 32 + (col - 64)] = v;
            } else {
              v = splus(v + p.b_post_stats[col - 64]) + 0.1f;
              orow[576 + col - 96] = v;
            }
          }
      }
    }
    grid.sync();
  }
}

extern "C" void kernel_launch(void* const* d_in, const int* in_sizes, int n_in,
                              void* d_out, int out_size, void* d_ws, size_t ws_size,
                              hipStream_t stream) {
  P p;
  p.obs = (const float*)d_in[0];
  p.action = (const float*)d_in[1];
  p.is_first = (const int*)d_in[2];
  p.w_prior_in = (const float*)d_in[3];
  p.g_prior_in = (const float*)d_in[4];
  p.bb_prior_in = (const float*)d_in[5];
  p.w_gru = (const float*)d_in[6];
  p.g_gru = (const float*)d_in[7];
  p.bb_gru = (const float*)d_in[8];
  p.w_prior_out = (const float*)d_in[9];
  p.g_prior_out = (const float*)d_in[10];
  p.bb_prior_out = (const float*)d_in[11];
  p.w_prior_stats = (const float*)d_in[12];
  p.b_prior_stats = (const float*)d_in[13];
  p.w_post = (const float*)d_in[14];
  p.g_post = (const float*)d_in[15];
  p.bb_post = (const float*)d_in[16];
  p.w_post_stats = (const float*)d_in[17];
  p.b_post_stats = (const float*)d_in[18];
  p.initial_deter = (const float*)d_in[19];
  p.out = (float*)d_out;

  char* w = (char*)d_ws;
  auto alloc = [&](size_t bytes) -> char* {
    char* r = w; w += (bytes + 255) & ~(size_t)255; return r;
  };
  p.WgT3 = (u16*)alloc((size_t)1536 * 3072 * 2);
  p.W2T3 = (u16*)alloc((size_t)1024 * 1632 * 2);
  p.WsT3 = (u16*)alloc((size_t)128 * 3072 * 2);
  p.deter0    = (float*)alloc(512 * 4);
  p.init_mean = (float*)alloc(32 * 4);
  p.deter = (float*)alloc((size_t)256 * 512 * 4);
  p.stoch = (float*)alloc((size_t)256 * 32 * 4);
  p.xg    = (u16*)alloc((size_t)256 * 3072 * 2);
  p.gates = (float*)alloc((size_t)256 * 1536 * 4);
  p.dox   = (u16*)alloc((size_t)256 * 1632 * 2);
  p.hraw  = (float*)alloc((size_t)256 * 1024 * 4);
  p.h2    = (u16*)alloc((size_t)256 * 3072 * 2);

  k_weights<<<dim3(256), dim3(256), 0, stream>>>(p);
  k_init_state<<<dim3(1), dim3(256), 0, stream>>>(p);
  void* args[] = { &p };
  hipLaunchCooperativeKernel(reinterpret_cast<void*>(&k_main), dim3(GRID), dim3(BDIM),
                             args, 0, stream);
}

// Round 4
// 10905.153 us; speedup vs baseline: 8.1004x; 8.1004x over previous
//
#include <hip/hip_runtime.h>
#include <hip/hip_cooperative_groups.h>

namespace cg = cooperative_groups;

#define TT 256      // timesteps
#define GRID 256
#define BDIM 256

typedef unsigned short u16;
typedef unsigned int u32;
typedef __attribute__((ext_vector_type(8))) short bf16x8;
typedef __attribute__((ext_vector_type(4))) float f32x4;

struct P {
  const float* obs; const float* action; const int* is_first;
  const float* w_prior_in; const float* g_prior_in; const float* bb_prior_in;
  const float* w_gru; const float* g_gru; const float* bb_gru;
  const float* w_prior_out; const float* g_prior_out; const float* bb_prior_out;
  const float* w_prior_stats; const float* b_prior_stats;
  const float* w_post; const float* g_post; const float* bb_post;
  const float* w_post_stats; const float* b_post_stats;
  const float* initial_deter;
  float* out;
  // split-bf16 weights, N-major, K-planes [hi | hi | lo]
  u16 *WgT3;    // [1536][3072]  (w_gru, K=1024)
  u16 *W2T3;    // [1024][1632]  (n<512: prior_out K=[deter512|pad32]; n>=512: post K=[deter512|obs18pad14])
  u16 *WsT3;    // [128][3072]   (n<64: prior_stats on h2[0:512]; n>=64: post_stats on h2[512:1024])
  float *deter0, *init_mean;
  int *segb, *segt0, *nact;     // segment bookkeeping (sorted by length desc)
  float *deter;   // [CH][512] fp32 state
  float *stoch;   // [CH][32]  fp32 state (posterior mean)
  u16 *xg;        // [CH][3072] A-planes [hi|lo|hi] of [h(512)|deter(512)]
  float *gates;   // [CH][1536] fp32
  u16 *dox;       // [CH][1632] A-planes [hi|lo|hi] of [deter(512)|obs(18)pad(14)]
  float *hraw;    // [CH][1024] fp32
  u16 *h2;        // [CH][3072] A-planes [hi|lo|hi] of silu(ln(hraw)) halves
  int CH;
};

__device__ __forceinline__ float b2f(u16 u) {
  union { float f; u32 i; } v; v.i = ((u32)u) << 16; return v.f;
}
__device__ __forceinline__ u16 f2b(float f) {
  union { float f; u32 i; } v; v.f = f;
  u32 r = v.i + 0x7FFF + ((v.i >> 16) & 1);   // RNE
  return (u16)(r >> 16);
}
__device__ __forceinline__ float sigm(float x) { return 1.f / (1.f + __expf(-x)); }
__device__ __forceinline__ float splus(float x) { return x > 15.f ? x : log1pf(__expf(x)); }

// ---- prior_in head (fp32 VALU): h = silu(ln(x @ Wpi)); writes xg h-planes for row i ----
__device__ __forceinline__ void h_from_x(const P& p, int i, float xv, int lane) {
  float a0[8];
  #pragma unroll
  for (int c = 0; c < 8; ++c) a0[c] = 0.f;
  #pragma unroll 4
  for (int j = 0; j < 36; ++j) {
    float s = __shfl(xv, j, 64);
    const float* wr = p.w_prior_in + j * 512 + lane;
    #pragma unroll
    for (int c = 0; c < 8; ++c) a0[c] = fmaf(s, wr[c << 6], a0[c]);
  }
  float sm = 0.f, sq = 0.f;
  #pragma unroll
  for (int c = 0; c < 8; ++c) { sm += a0[c]; sq += a0[c] * a0[c]; }
  #pragma unroll
  for (int o = 32; o; o >>= 1) { sm += __shfl_xor(sm, o); sq += __shfl_xor(sq, o); }
  float m = sm * (1.f / 512.f);
  float rs = rsqrtf(sq * (1.f / 512.f) - m * m + 1e-3f);
  size_t rowb = (size_t)i * 3072;
  #pragma unroll
  for (int c = 0; c < 8; ++c) {
    int col = lane + (c << 6);
    float v = (a0[c] - m) * rs * p.g_prior_in[col] + p.bb_prior_in[col];
    v = v * sigm(v);
    u16 hi = f2b(v); u16 lo = f2b(v - b2f(hi));
    p.xg[rowb + col] = hi;
    p.xg[rowb + 1024 + col] = lo;
    p.xg[rowb + 2048 + col] = hi;
  }
}

// ================= prep kernels =================
__global__ void k_weights(P p) {
  const int E1 = 1536 * 1024, E2 = 1024 * 544, E3 = 128 * 1024;
  const int total = E1 + E2 + E3;
  for (int idx = blockIdx.x * blockDim.x + threadIdx.x; idx < total;
       idx += gridDim.x * blockDim.x) {
    float w; u16* dst; int kk, kappa;
    if (idx < E1) {
      int n = idx >> 10; kk = idx & 1023; kappa = 1024;
      w = p.w_gru[kk * 1536 + n];
      dst = p.WgT3 + (size_t)n * 3072;
    } else if (idx < E1 + E2) {
      int t = idx - E1; int n = t / 544; kk = t - n * 544; kappa = 544;
      if (n < 512) w = (kk < 512) ? p.w_prior_out[kk * 512 + n] : 0.f;
      else         w = (kk < 530) ? p.w_post[kk * 512 + (n - 512)] : 0.f;
      dst = p.W2T3 + (size_t)n * 1632;
    } else {
      int t = idx - E1 - E2; int n = t >> 10; kk = t & 1023; kappa = 1024;
      if (n < 64) w = (kk < 512) ? p.w_prior_stats[kk * 64 + n] : 0.f;
      else        w = (kk >= 512) ? p.w_post_stats[(kk - 512) * 64 + (n - 64)] : 0.f;
      dst = p.WsT3 + (size_t)n * 3072;
    }
    u16 hi = f2b(w); u16 lo = f2b(w - b2f(hi));
    dst[kk] = hi; dst[kappa + kk] = hi; dst[2 * kappa + kk] = lo;
  }
}

__global__ void k_init_state(P p) {
  __shared__ float d0s[512], tmp[512], red[256];
  int tid = threadIdx.x;
  for (int n = tid; n < 512; n += 256) { d0s[n] = tanhf(p.initial_deter[n]); p.deter0[n] = d0s[n]; }
  __syncthreads();
  for (int n = tid; n < 512; n += 256) {
    float s = 0.f;
    for (int d = 0; d < 512; ++d) s = fmaf(d0s[d], p.w_prior_out[d * 512 + n], s);
    tmp[n] = s;
  }
  __syncthreads();
  float ls = 0.f, lq = 0.f;
  for (int n = tid; n < 512; n += 256) { ls += tmp[n]; lq += tmp[n] * tmp[n]; }
  red[tid] = ls; __syncthreads();
  for (int s = 128; s; s >>= 1) { if (tid < s) red[tid] += red[tid + s]; __syncthreads(); }
  float m = red[0] * (1.f / 512.f); __syncthreads();
  red[tid] = lq; __syncthreads();
  for (int s = 128; s; s >>= 1) { if (tid < s) red[tid] += red[tid + s]; __syncthreads(); }
  float rs = rsqrtf(red[0] * (1.f / 512.f) - m * m + 1e-3f); __syncthreads();
  for (int n = tid; n < 512; n += 256) {
    float h = (tmp[n] - m) * rs * p.g_prior_out[n] + p.bb_prior_out[n];
    tmp[n] = h * sigm(h);
  }
  __syncthreads();
  if (tid < 32) {
    float s = 0.f;
    for (int d = 0; d < 512; ++d) s = fmaf(tmp[d], p.w_prior_stats[d * 64 + tid], s);
    p.init_mean[tid] = s + p.b_prior_stats[tid];
  }
}

__global__ void k_segments(P p) {
  __shared__ int hist[257], off[258], cur[257];
  int tid = threadIdx.x;
  for (int i = tid; i < 257; i += 256) hist[i] = 0;
  __syncthreads();
  int b = tid;
  { int t = 0;
    while (t < TT) {
      int t0 = t; t++;
      while (t < TT && p.is_first[b * TT + t] == 0) t++;
      atomicAdd(&hist[t - t0], 1);
    } }
  __syncthreads();
  if (tid == 0) {
    int run = 0;
    for (int len = 256; len >= 0; --len) { off[len] = run; run += hist[len]; }
  }
  __syncthreads();
  for (int i = tid; i < 257; i += 256) { cur[i] = off[i]; p.nact[i] = off[i]; }
  __syncthreads();
  { int t = 0;
    while (t < TT) {
      int t0 = t; t++;
      while (t < TT && p.is_first[b * TT + t] == 0) t++;
      int idx = atomicAdd(&cur[t - t0], 1);
      p.segb[idx] = b; p.segt0[idx] = t0;
    } }
}

// ---- generic 128x128-tile split-bf16 GEMM: C = A3 @ B3^T (fp32 out) ----
__device__ void gemm_tiles(const u16* A, int lda, const u16* B, int ldb,
                           float* C, int ldc, int M, int ntn, int K3,
                           u16* Ab, u16* Bb, int bid, int nb, int tid) {
  const int wave = tid >> 6, lane = tid & 63, quad = lane >> 4, l15 = lane & 15;
  const int wr = (wave & 1) << 6, wc = (wave >> 1) << 6;
  const int ntm = (M + 127) >> 7;
  const int njobs = ntm * ntn;
  for (int j = bid; j < njobs; j += nb) {
    int tm = j / ntn, tn = j - tm * ntn;
    int r0 = tm << 7, c0 = tn << 7;
    f32x4 acc[4][4];
    #pragma unroll
    for (int a = 0; a < 4; ++a)
      #pragma unroll
      for (int bq = 0; bq < 4; ++bq) acc[a][bq] = f32x4{0.f, 0.f, 0.f, 0.f};
    for (int k0 = 0; k0 < K3; k0 += 32) {
      __syncthreads();
      #pragma unroll
      for (int s = 0; s < 2; ++s) {
        int ch = tid + (s << 8);
        int row = ch >> 2, ko = (ch & 3) << 3;
        *(uint4*)&Ab[(row << 5) + ko] =
            *(const uint4*)(A + (size_t)(r0 + row) * lda + k0 + ko);
        *(uint4*)&Bb[(row << 5) + ko] =
            *(const uint4*)(B + (size_t)(c0 + row) * ldb + k0 + ko);
      }
      __syncthreads();
      bf16x8 af[4], bf[4];
      #pragma unroll
      for (int s2 = 0; s2 < 4; ++s2) {
        af[s2] = *(const bf16x8*)&Ab[((wr + (s2 << 4) + l15) << 5) + (quad << 3)];
        bf[s2] = *(const bf16x8*)&Bb[((wc + (s2 << 4) + l15) << 5) + (quad << 3)];
      }
      #pragma unroll
      for (int mi = 0; mi < 4; ++mi)
        #pragma unroll
        for (int ni = 0; ni < 4; ++ni)
          acc[mi][ni] = __builtin_amdgcn_mfma_f32_16x16x32_bf16(af[mi], bf[ni], acc[mi][ni], 0, 0, 0);
    }
    #pragma unroll
    for (int mi = 0; mi < 4; ++mi)
      #pragma unroll
      for (int ni = 0; ni < 4; ++ni)
        #pragma unroll
        for (int r = 0; r < 4; ++r)
          C[(size_t)(r0 + wr + (mi << 4) + (quad << 2) + r) * ldc
            + c0 + wc + (ni << 4) + l15] = acc[mi][ni][r];
  }
}

// ================= main cooperative kernel: k-loop over sorted segments =================
__global__ void __launch_bounds__(BDIM, 2) k_main(P p) {
  cg::grid_group grid = cg::this_grid();
  __shared__ u16 Ab[128 * 32], Bb[128 * 32];
  const int tid = threadIdx.x;
  const int bid = blockIdx.x, nb = gridDim.x;
  const int wave = tid >> 6, lane = tid & 63, quad = lane >> 4, l15 = lane & 15;
  const int gw = (bid << 2) + wave, nwv = nb << 2;
  const int CH = p.CH;
  const int S_total = p.nact[0];

  for (int base = 0; base < S_total; base += CH) {
    for (int k = 0;; ++k) {
      int Sk = p.nact[k] - base; Sk = Sk > CH ? CH : Sk;
      if (Sk <= 0) break;

      // ---- A: (k==0: state init) + prior_in head from carried stoch ----
      for (int i = gw; i < Sk; i += nwv) {
        int gi = base + i;
        int b = p.segb[gi], t0 = p.segt0[gi];
        float xv = 0.f;
        if (k == 0) {
          size_t rowb = (size_t)i * 3072;
          #pragma unroll
          for (int c = 0; c < 8; ++c) {
            int d = lane + (c << 6);
            float v = p.deter0[d];
            p.deter[(size_t)i * 512 + d] = v;
            u16 hi = f2b(v); u16 lo = f2b(v - b2f(hi));
            p.xg[rowb + 512 + d] = hi;
            p.xg[rowb + 1536 + d] = lo;
            p.xg[rowb + 2560 + d] = hi;
          }
          int ff = p.is_first[b * TT + t0];
          if (lane < 32) xv = p.init_mean[lane];
          else if (lane < 36) xv = (ff > 0) ? 0.f : p.action[((size_t)b * TT + t0) * 4 + (lane - 32)];
        } else {
          if (lane < 32) xv = p.stoch[(size_t)i * 32 + lane];
          else if (lane < 36) xv = p.action[((size_t)b * TT + t0 + k) * 4 + (lane - 32)];
        }
        h_from_x(p, i, xv, lane);
      }
      grid.sync();

      // ---- B: gates = xg3 @ WgT3  (Sk x 1536, K3=3072) ----
      gemm_tiles(p.xg, 3072, p.WgT3, 3072, p.gates, 1536, Sk, 12, 3072,
                 Ab, Bb, bid, nb, tid);
      grid.sync();

      // ---- C: LN(gates) -> GRU update -> deter', out-deter, xg/dox refresh ----
      for (int i = gw; i < Sk; i += nwv) {
        const float* grow = p.gates + (size_t)i * 1536;
        float g[24];
        float sm = 0.f, sq = 0.f;
        #pragma unroll
        for (int c = 0; c < 24; ++c) {
          g[c] = grow[lane + (c << 6)];
          sm += g[c]; sq += g[c] * g[c];
        }
        #pragma unroll
        for (int o = 32; o; o >>= 1) { sm += __shfl_xor(sm, o); sq += __shfl_xor(sq, o); }
        float m = sm * (1.f / 1536.f);
        float rs = rsqrtf(sq * (1.f / 1536.f) - m * m + 1e-3f);
        int gi = base + i;
        int b = p.segb[gi], t = p.segt0[gi] + k;
        float* orow = p.out + ((size_t)b * TT + t) * 1216;
        size_t rowx = (size_t)i * 3072, rowd = (size_t)i * 1632;
        #pragma unroll
        for (int c = 0; c < 8; ++c) {
          int d = lane + (c << 6);
          float gr = (g[c]      - m) * rs * p.g_gru[d]        + p.bb_gru[d];
          float gc = (g[c + 8]  - m) * rs * p.g_gru[512 + d]  + p.bb_gru[512 + d];
          float gu = (g[c + 16] - m) * rs * p.g_gru[1024 + d] + p.bb_gru[1024 + d];
          float r_ = sigm(gr);
          float u_ = sigm(gu - 1.0f);
          float rc = r_ * gc;
          float cand = rc * sigm(rc);
          float dp = p.deter[(size_t)i * 512 + d];
          float dn = u_ * cand + (1.f - u_) * dp;
          p.deter[(size_t)i * 512 + d] = dn;
          orow[d] = dn; orow[608 + d] = dn;
          u16 hi = f2b(dn); u16 lo = f2b(dn - b2f(hi));
          p.xg[rowx + 512 + d] = hi;
          p.xg[rowx + 1536 + d] = lo;
          p.xg[rowx + 2560 + d] = hi;
          p.dox[rowd + d] = hi;
          p.dox[rowd + 544 + d] = lo;
          p.dox[rowd + 1088 + d] = hi;
        }
        if (lane < 32) {
          float ov = (lane < 18) ? p.obs[((size_t)b * TT + t) * 18 + lane] : 0.f;
          u16 hi = f2b(ov); u16 lo = f2b(ov - b2f(hi));
          p.dox[rowd + 512 + lane] = hi;
          p.dox[rowd + 1056 + lane] = lo;
          p.dox[rowd + 1600 + lane] = hi;
        }
      }
      grid.sync();

      // ---- D: hraw = dox3 @ W2T3  (Sk x 1024, K3=1632) ----
      gemm_tiles(p.dox, 1632, p.W2T3, 1632, p.hraw, 1024, Sk, 8, 1632,
                 Ab, Bb, bid, nb, tid);
      grid.sync();

      // ---- E: two LNs + silu -> h2 planes ----
      for (int i = gw; i < Sk; i += nwv) {
        size_t rowh = (size_t)i * 3072;
        #pragma unroll
        for (int hh = 0; hh < 2; ++hh) {
          const float* hb = p.hraw + (size_t)i * 1024 + (hh << 9);
          const float* gv = hh ? p.g_post : p.g_prior_out;
          const float* bv = hh ? p.bb_post : p.bb_prior_out;
          float v[8];
          float sm = 0.f, sq = 0.f;
          #pragma unroll
          for (int c = 0; c < 8; ++c) {
            v[c] = hb[lane + (c << 6)];
            sm += v[c]; sq += v[c] * v[c];
          }
          #pragma unroll
          for (int o = 32; o; o >>= 1) { sm += __shfl_xor(sm, o); sq += __shfl_xor(sq, o); }
          float m = sm * (1.f / 512.f);
          float rs = rsqrtf(sq * (1.f / 512.f) - m * m + 1e-3f);
          #pragma unroll
          for (int c = 0; c < 8; ++c) {
            int d = lane + (c << 6);
            float x = (v[c] - m) * rs * gv[d] + bv[d];
            x = x * sigm(x);
            int col = (hh << 9) + d;
            u16 hi = f2b(x); u16 lo = f2b(x - b2f(hi));
            p.h2[rowh + col] = hi;
            p.h2[rowh + 1024 + col] = lo;
            p.h2[rowh + 2048 + col] = hi;
          }
        }
      }
      grid.sync();

      // ---- F: stats = h2 @ WsT3 (32-row tiles, N=128, K3=3072) + epilogue ----
      {
        const int sr = (wave & 1) << 4, sc = (wave >> 1) << 6;
        int njobs = (Sk + 31) >> 5;
        for (int j = bid; j < njobs; j += nb) {
          int r0 = j << 5;
          f32x4 acc[4];
          #pragma unroll
          for (int z = 0; z < 4; ++z) acc[z] = f32x4{0.f, 0.f, 0.f, 0.f};
          for (int k0 = 0; k0 < 3072; k0 += 32) {
            __syncthreads();
            if (tid < 128) {
              int row = tid >> 2, ko = (tid & 3) << 3;
              *(uint4*)&Ab[(row << 5) + ko] =
                  *(const uint4*)(p.h2 + (size_t)(r0 + row) * 3072 + k0 + ko);
            }
            #pragma unroll
            for (int s = 0; s < 2; ++s) {
              int ch = tid + (s << 8);
              int row = ch >> 2, ko = (ch & 3) << 3;
              *(uint4*)&Bb[(row << 5) + ko] =
                  *(const uint4*)(p.WsT3 + (size_t)row * 3072 + k0 + ko);
            }
            __syncthreads();
            bf16x8 af = *(const bf16x8*)&Ab[((sr + l15) << 5) + (quad << 3)];
            #pragma unroll
            for (int ns = 0; ns < 4; ++ns) {
              bf16x8 bf = *(const bf16x8*)&Bb[((sc + (ns << 4) + l15) << 5) + (quad << 3)];
              acc[ns] = __builtin_amdgcn_mfma_f32_16x16x32_bf16(af, bf, acc[ns], 0, 0, 0);
            }
          }
          #pragma unroll
          for (int ns = 0; ns < 4; ++ns)
            #pragma unroll
            for (int r = 0; r < 4; ++r) {
              int i = r0 + sr + (quad << 2) + r;
              int col = sc + (ns << 4) + l15;
              if (i < Sk) {
                float v = acc[ns][r];
                int gi = base + i;
                int b = p.segb[gi], t = p.segt0[gi] + k;
                float* orow = p.out + ((size_t)b * TT + t) * 1216;
                if (col < 32) {
                  v += p.b_prior_stats[col];
                  orow[1120 + col] = v; orow[1152 + col] = v;
                } else if (col < 64) {
                  v = splus(v + p.b_prior_stats[col]) + 0.1f;
                  orow[1184 + col - 32] = v;
                } else if (col < 96) {
                  v += p.b_post_stats[col - 64];
                  orow[512 + col - 64] = v; orow[544 + col - 64] = v;
                  p.stoch[(size_t)i * 32 + (col - 64)] = v;
                } else {
                  v = splus(v + p.b_post_stats[col - 64]) + 0.1f;
                  orow[576 + col - 96] = v;
                }
              }
            }
        }
      }
      grid.sync();
    }
  }
}

extern "C" void kernel_launch(void* const* d_in, const int* in_sizes, int n_in,
                              void* d_out, int out_size, void* d_ws, size_t ws_size,
                              hipStream_t stream) {
  P p;
  p.obs = (const float*)d_in[0];
  p.action = (const float*)d_in[1];
  p.is_first = (const int*)d_in[2];
  p.w_prior_in = (const float*)d_in[3];
  p.g_prior_in = (const float*)d_in[4];
  p.bb_prior_in = (const float*)d_in[5];
  p.w_gru = (const float*)d_in[6];
  p.g_gru = (const float*)d_in[7];
  p.bb_gru = (const float*)d_in[8];
  p.w_prior_out = (const float*)d_in[9];
  p.g_prior_out = (const float*)d_in[10];
  p.bb_prior_out = (const float*)d_in[11];
  p.w_prior_stats = (const float*)d_in[12];
  p.b_prior_stats = (const float*)d_in[13];
  p.w_post = (const float*)d_in[14];
  p.g_post = (const float*)d_in[15];
  p.bb_post = (const float*)d_in[16];
  p.w_post_stats = (const float*)d_in[17];
  p.b_post_stats = (const float*)d_in[18];
  p.initial_deter = (const float*)d_in[19];
  p.out = (float*)d_out;

  char* w = (char*)d_ws;
  auto alloc = [&](size_t bytes) -> char* {
    char* r = w; w += (bytes + 255) & ~(size_t)255; return r;
  };
  p.WgT3 = (u16*)alloc((size_t)1536 * 3072 * 2);
  p.W2T3 = (u16*)alloc((size_t)1024 * 1632 * 2);
  p.WsT3 = (u16*)alloc((size_t)128 * 3072 * 2);
  p.deter0    = (float*)alloc(512 * 4);
  p.init_mean = (float*)alloc(32 * 4);
  p.segb  = (int*)alloc((size_t)65536 * 4);
  p.segt0 = (int*)alloc((size_t)65536 * 4);
  p.nact  = (int*)alloc(257 * 4);
  size_t used = (size_t)(w - (char*)d_ws);
  size_t avail = ws_size > used ? ws_size - used : 0;
  // per-row: deter 2048 + stoch 128 + xg 6144 + gates 6144 + dox 3264 + hraw 4096 + h2 6144 = 27968 B
  long long ch = (long long)(avail / 28672);
  if (ch > 8192) ch = 8192;
  ch &= ~127LL;
  if (ch < 128) ch = 128;
  p.CH = (int)ch;
  p.deter = (float*)alloc((size_t)p.CH * 512 * 4);
  p.stoch = (float*)alloc((size_t)p.CH * 32 * 4);
  p.xg    = (u16*)alloc((size_t)p.CH * 3072 * 2);
  p.gates = (float*)alloc((size_t)p.CH * 1536 * 4);
  p.dox   = (u16*)alloc((size_t)p.CH * 1632 * 2);
  p.hraw  = (float*)alloc((size_t)p.CH * 1024 * 4);
  p.h2    = (u16*)alloc((size_t)p.CH * 3072 * 2);

  k_weights<<<dim3(256), dim3(256), 0, stream>>>(p);
  k_init_state<<<dim3(1), dim3(256), 0, stream>>>(p);
  k_segments<<<dim3(1), dim3(256), 0, stream>>>(p);
  void* args[] = { &p };
  hipLaunchCooperativeKernel(reinterpret_cast<void*>(&k_main), dim3(GRID), dim3(BDIM),
                             args, 0, stream);
}

// Round 6
// 10578.529 us; speedup vs baseline: 8.3505x; 1.0309x over previous
//
#include <hip/hip_runtime.h>
#include <hip/hip_cooperative_groups.h>

namespace cg = cooperative_groups;

#define TT 256      // timesteps
#define GRID 256    // cooperative launch: 512 blocks is REJECTED on this kernel (1 block/CU cap);
                    // rounds 1/2/5 all silently no-op'd at GRID=512. Keep <=256.
#define BDIM 256

typedef unsigned short u16;
typedef unsigned int u32;
typedef __attribute__((ext_vector_type(8))) short bf16x8;
typedef __attribute__((ext_vector_type(4))) float f32x4;

// async global->LDS, 16B per lane; LDS dest is wave-uniform base + lane*16
#define GLL(g, l) __builtin_amdgcn_global_load_lds( \
    (const __attribute__((address_space(1))) void*)(g), \
    (__attribute__((address_space(3))) void*)(l), 16, 0, 0)

struct P {
  const float* obs; const float* action; const int* is_first;
  const float* w_prior_in; const float* g_prior_in; const float* bb_prior_in;
  const float* w_gru; const float* g_gru; const float* bb_gru;
  const float* w_prior_out; const float* g_prior_out; const float* bb_prior_out;
  const float* w_prior_stats; const float* b_prior_stats;
  const float* w_post; const float* g_post; const float* bb_post;
  const float* w_post_stats; const float* b_post_stats;
  const float* initial_deter;
  float* out;
  // split-bf16 weights, N-major, K-planes [hi | hi | lo]
  u16 *WgT3;    // [1536][3072]  (w_gru, K=1024)
  u16 *W2T3;    // [1024][1632]  (n<512: prior_out K=[deter512|pad32]; n>=512: post K=[deter512|obs18pad14])
  u16 *WsT3;    // [128][3072]   (n<64: prior_stats on h2[0:512]; n>=64: post_stats on h2[512:1024])
  float *deter0, *init_mean;
  int *segb, *segt0, *nact;     // segment bookkeeping (sorted by length desc)
  float *deter;   // [CH][512] fp32 state
  float *stoch;   // [CH][32]  fp32 state (posterior mean)
  u16 *xg;        // [CH][3072] A-planes [hi|lo|hi] of [h(512)|deter(512)]
  float *gates;   // [CH][1536] fp32
  u16 *dox;       // [CH][1632] A-planes [hi|lo|hi] of [deter(512)|obs(18)pad(14)]
  float *hraw;    // [CH][1024] fp32
  u16 *h2;        // [CH][3072] A-planes [hi|lo|hi] of silu(ln(hraw)) halves
  int CH;
};

__device__ __forceinline__ float b2f(u16 u) {
  union { float f; u32 i; } v; v.i = ((u32)u) << 16; return v.f;
}
__device__ __forceinline__ u16 f2b(float f) {
  union { float f; u32 i; } v; v.f = f;
  u32 r = v.i + 0x7FFF + ((v.i >> 16) & 1);   // RNE
  return (u16)(r >> 16);
}
__device__ __forceinline__ float sigm(float x) { return 1.f / (1.f + __expf(-x)); }
__device__ __forceinline__ float splus(float x) { return x > 15.f ? x : log1pf(__expf(x)); }

// ---- prior_in head (fp32 VALU): h = silu(ln(x @ Wpi)); writes xg h-planes for row i ----
__device__ __forceinline__ void h_from_x(const P& p, int i, float xv, int lane) {
  float a0[8];
  #pragma unroll
  for (int c = 0; c < 8; ++c) a0[c] = 0.f;
  #pragma unroll 4
  for (int j = 0; j < 36; ++j) {
    float s = __shfl(xv, j, 64);
    const float* wr = p.w_prior_in + j * 512 + lane;
    #pragma unroll
    for (int c = 0; c < 8; ++c) a0[c] = fmaf(s, wr[c << 6], a0[c]);
  }
  float sm = 0.f, sq = 0.f;
  #pragma unroll
  for (int c = 0; c < 8; ++c) { sm += a0[c]; sq += a0[c] * a0[c]; }
  #pragma unroll
  for (int o = 32; o; o >>= 1) { sm += __shfl_xor(sm, o); sq += __shfl_xor(sq, o); }
  float m = sm * (1.f / 512.f);
  float rs = rsqrtf(sq * (1.f / 512.f) - m * m + 1e-3f);
  size_t rowb = (size_t)i * 3072;
  #pragma unroll
  for (int c = 0; c < 8; ++c) {
    int col = lane + (c << 6);
    float v = (a0[c] - m) * rs * p.g_prior_in[col] + p.bb_prior_in[col];
    v = v * sigm(v);
    u16 hi = f2b(v); u16 lo = f2b(v - b2f(hi));
    p.xg[rowb + col] = hi;
    p.xg[rowb + 1024 + col] = lo;
    p.xg[rowb + 2048 + col] = hi;
  }
}

// ================= prep kernels =================
__global__ void k_weights(P p) {
  const int E1 = 1536 * 1024, E2 = 1024 * 544, E3 = 128 * 1024;
  const int total = E1 + E2 + E3;
  for (int idx = blockIdx.x * blockDim.x + threadIdx.x; idx < total;
       idx += gridDim.x * blockDim.x) {
    float w; u16* dst; int kk, kappa;
    if (idx < E1) {
      int n = idx >> 10; kk = idx & 1023; kappa = 1024;
      w = p.w_gru[kk * 1536 + n];
      dst = p.WgT3 + (size_t)n * 3072;
    } else if (idx < E1 + E2) {
      int t = idx - E1; int n = t / 544; kk = t - n * 544; kappa = 544;
      if (n < 512) w = (kk < 512) ? p.w_prior_out[kk * 512 + n] : 0.f;
      else         w = (kk < 530) ? p.w_post[kk * 512 + (n - 512)] : 0.f;
      dst = p.W2T3 + (size_t)n * 1632;
    } else {
      int t = idx - E1 - E2; int n = t >> 10; kk = t & 1023; kappa = 1024;
      if (n < 64) w = (kk < 512) ? p.w_prior_stats[kk * 64 + n] : 0.f;
      else        w = (kk >= 512) ? p.w_post_stats[(kk - 512) * 64 + (n - 64)] : 0.f;
      dst = p.WsT3 + (size_t)n * 3072;
    }
    u16 hi = f2b(w); u16 lo = f2b(w - b2f(hi));
    dst[kk] = hi; dst[kappa + kk] = hi; dst[2 * kappa + kk] = lo;
  }
}

__global__ void k_init_state(P p) {
  __shared__ float d0s[512], tmp[512], red[256];
  int tid = threadIdx.x;
  for (int n = tid; n < 512; n += 256) { d0s[n] = tanhf(p.initial_deter[n]); p.deter0[n] = d0s[n]; }
  __syncthreads();
  for (int n = tid; n < 512; n += 256) {
    float s = 0.f;
    for (int d = 0; d < 512; ++d) s = fmaf(d0s[d], p.w_prior_out[d * 512 + n], s);
    tmp[n] = s;
  }
  __syncthreads();
  float ls = 0.f, lq = 0.f;
  for (int n = tid; n < 512; n += 256) { ls += tmp[n]; lq += tmp[n] * tmp[n]; }
  red[tid] = ls; __syncthreads();
  for (int s = 128; s; s >>= 1) { if (tid < s) red[tid] += red[tid + s]; __syncthreads(); }
  float m = red[0] * (1.f / 512.f); __syncthreads();
  red[tid] = lq; __syncthreads();
  for (int s = 128; s; s >>= 1) { if (tid < s) red[tid] += red[tid + s]; __syncthreads(); }
  float rs = rsqrtf(red[0] * (1.f / 512.f) - m * m + 1e-3f); __syncthreads();
  for (int n = tid; n < 512; n += 256) {
    float h = (tmp[n] - m) * rs * p.g_prior_out[n] + p.bb_prior_out[n];
    tmp[n] = h * sigm(h);
  }
  __syncthreads();
  if (tid < 32) {
    float s = 0.f;
    for (int d = 0; d < 512; ++d) s = fmaf(tmp[d], p.w_prior_stats[d * 64 + tid], s);
    p.init_mean[tid] = s + p.b_prior_stats[tid];
  }
}

__global__ void k_segments(P p) {
  __shared__ int hist[257], off[258], cur[257];
  int tid = threadIdx.x;
  for (int i = tid; i < 257; i += 256) hist[i] = 0;
  __syncthreads();
  int b = tid;
  { int t = 0;
    while (t < TT) {
      int t0 = t; t++;
      while (t < TT && p.is_first[b * TT + t] == 0) t++;
      atomicAdd(&hist[t - t0], 1);
    } }
  __syncthreads();
  if (tid == 0) {
    int run = 0;
    for (int len = 256; len >= 0; --len) { off[len] = run; run += hist[len]; }
  }
  __syncthreads();
  for (int i = tid; i < 257; i += 256) { cur[i] = off[i]; p.nact[i] = off[i]; }
  __syncthreads();
  { int t = 0;
    while (t < TT) {
      int t0 = t; t++;
      while (t < TT && p.is_first[b * TT + t] == 0) t++;
      int idx = atomicAdd(&cur[t - t0], 1);
      p.segb[idx] = b; p.segt0[idx] = t0;
    } }
}

// ---- generic 128x128-tile split-bf16 GEMM, double-buffered async staging ----
// LDS arena (u16 elems): A buf0 [0,4096) buf1 [4096,8192); B buf0 [8192,12288) buf1 [12288,16384)
__device__ void gemm_tiles(const u16* A, int lda, const u16* B, int ldb,
                           float* C, int ldc, int M, int ntn, int K3,
                           u16* lds, int bid, int nb, int tid) {
  const int wave = tid >> 6, lane = tid & 63, quad = lane >> 4, l15 = lane & 15;
  const int wr = (wave & 1) << 6, wc = (wave >> 1) << 6;
  const int ntm = (M + 127) >> 7;
  const int njobs = ntm * ntn;
  const int row0 = tid >> 2, ko0 = (tid & 3) << 3;   // s=0 chunk; s=1 is row0+64
  u16* const la0 = lds + (wave << 9);
  u16* const la1 = lds + 2048 + (wave << 9);
  u16* const lb0 = lds + 8192 + (wave << 9);
  u16* const lb1 = lds + 8192 + 2048 + (wave << 9);
  for (int j = bid; j < njobs; j += nb) {
    int tm = j / ntn, tn = j - tm * ntn;
    int r0 = tm << 7, c0 = tn << 7;
    const u16* ga0 = A + (size_t)(r0 + row0) * lda + ko0;
    const u16* ga1 = A + (size_t)(r0 + row0 + 64) * lda + ko0;
    const u16* gb0 = B + (size_t)(c0 + row0) * ldb + ko0;
    const u16* gb1 = B + (size_t)(c0 + row0 + 64) * ldb + ko0;
    f32x4 acc[4][4];
    #pragma unroll
    for (int a = 0; a < 4; ++a)
      #pragma unroll
      for (int bq = 0; bq < 4; ++bq) acc[a][bq] = f32x4{0.f, 0.f, 0.f, 0.f};
    __syncthreads();                      // WAR: prev job's LDS reads done
    GLL(ga0, la0); GLL(ga1, la1); GLL(gb0, lb0); GLL(gb1, lb1);   // prologue -> buf0
    int buf = 0;
    for (int k0 = 0; k0 < K3; k0 += 32) {
      __syncthreads();                    // drains vmcnt -> buf ready
      if (k0 + 32 < K3) {
        int bo = (buf ^ 1) << 12;
        int o = k0 + 32;
        GLL(ga0 + o, la0 + bo); GLL(ga1 + o, la1 + bo);
        GLL(gb0 + o, lb0 + bo); GLL(gb1 + o, lb1 + bo);
      }
      const u16* Ab = lds + (buf << 12);
      const u16* Bb = lds + 8192 + (buf << 12);
      bf16x8 af[4], bf[4];
      #pragma unroll
      for (int s2 = 0; s2 < 4; ++s2) {
        af[s2] = *(const bf16x8*)&Ab[((wr + (s2 << 4) + l15) << 5) + (quad << 3)];
        bf[s2] = *(const bf16x8*)&Bb[((wc + (s2 << 4) + l15) << 5) + (quad << 3)];
      }
      #pragma unroll
      for (int mi = 0; mi < 4; ++mi)
        #pragma unroll
        for (int ni = 0; ni < 4; ++ni)
          acc[mi][ni] = __builtin_amdgcn_mfma_f32_16x16x32_bf16(af[mi], bf[ni], acc[mi][ni], 0, 0, 0);
      buf ^= 1;
    }
    #pragma unroll
    for (int mi = 0; mi < 4; ++mi)
      #pragma unroll
      for (int ni = 0; ni < 4; ++ni)
        #pragma unroll
        for (int r = 0; r < 4; ++r)
          C[(size_t)(r0 + wr + (mi << 4) + (quad << 2) + r) * ldc
            + c0 + wc + (ni << 4) + l15] = acc[mi][ni][r];
  }
}

// ================= main cooperative kernel: k-loop over sorted segments =================
__global__ void __launch_bounds__(BDIM, 2) k_main(P p) {
  cg::grid_group grid = cg::this_grid();
  __shared__ u16 lds[16384];   // 32 KB staging arena
  const int tid = threadIdx.x;
  const int bid = blockIdx.x, nb = gridDim.x;
  const int wave = tid >> 6, lane = tid & 63, quad = lane >> 4, l15 = lane & 15;
  const int gw = (bid << 2) + wave, nwv = nb << 2;
  const int CH = p.CH;
  const int S_total = p.nact[0];

  for (int base = 0; base < S_total; base += CH) {
    for (int k = 0;; ++k) {
      int Sk = p.nact[k] - base; Sk = Sk > CH ? CH : Sk;
      if (Sk <= 0) break;

      // ---- A: (k==0: state init) + prior_in head from carried stoch ----
      for (int i = gw; i < Sk; i += nwv) {
        int gi = base + i;
        int b = p.segb[gi], t0 = p.segt0[gi];
        float xv = 0.f;
        if (k == 0) {
          size_t rowb = (size_t)i * 3072;
          #pragma unroll
          for (int c = 0; c < 8; ++c) {
            int d = lane + (c << 6);
            float v = p.deter0[d];
            p.deter[(size_t)i * 512 + d] = v;
            u16 hi = f2b(v); u16 lo = f2b(v - b2f(hi));
            p.xg[rowb + 512 + d] = hi;
            p.xg[rowb + 1536 + d] = lo;
            p.xg[rowb + 2560 + d] = hi;
          }
          int ff = p.is_first[b * TT + t0];
          if (lane < 32) xv = p.init_mean[lane];
          else if (lane < 36) xv = (ff > 0) ? 0.f : p.action[((size_t)b * TT + t0) * 4 + (lane - 32)];
        } else {
          if (lane < 32) xv = p.stoch[(size_t)i * 32 + lane];
          else if (lane < 36) xv = p.action[((size_t)b * TT + t0 + k) * 4 + (lane - 32)];
        }
        h_from_x(p, i, xv, lane);
      }
      grid.sync();

      // ---- B: gates = xg3 @ WgT3  (Sk x 1536, K3=3072) ----
      gemm_tiles(p.xg, 3072, p.WgT3, 3072, p.gates, 1536, Sk, 12, 3072,
                 lds, bid, nb, tid);
      grid.sync();

      // ---- C: LN(gates) -> GRU update -> deter', out-deter, xg/dox refresh ----
      for (int i = gw; i < Sk; i += nwv) {
        const float* grow = p.gates + (size_t)i * 1536;
        float g[24];
        float sm = 0.f, sq = 0.f;
        #pragma unroll
        for (int c = 0; c < 24; ++c) {
          g[c] = grow[lane + (c << 6)];
          sm += g[c]; sq += g[c] * g[c];
        }
        #pragma unroll
        for (int o = 32; o; o >>= 1) { sm += __shfl_xor(sm, o); sq += __shfl_xor(sq, o); }
        float m = sm * (1.f / 1536.f);
        float rs = rsqrtf(sq * (1.f / 1536.f) - m * m + 1e-3f);
        int gi = base + i;
        int b = p.segb[gi], t = p.segt0[gi] + k;
        float* orow = p.out + ((size_t)b * TT + t) * 1216;
        size_t rowx = (size_t)i * 3072, rowd = (size_t)i * 1632;
        #pragma unroll
        for (int c = 0; c < 8; ++c) {
          int d = lane + (c << 6);
          float gr = (g[c]      - m) * rs * p.g_gru[d]        + p.bb_gru[d];
          float gc = (g[c + 8]  - m) * rs * p.g_gru[512 + d]  + p.bb_gru[512 + d];
          float gu = (g[c + 16] - m) * rs * p.g_gru[1024 + d] + p.bb_gru[1024 + d];
          float r_ = sigm(gr);
          float u_ = sigm(gu - 1.0f);
          float rc = r_ * gc;
          float cand = rc * sigm(rc);
          float dp = p.deter[(size_t)i * 512 + d];
          float dn = u_ * cand + (1.f - u_) * dp;
          p.deter[(size_t)i * 512 + d] = dn;
          orow[d] = dn; orow[608 + d] = dn;
          u16 hi = f2b(dn); u16 lo = f2b(dn - b2f(hi));
          p.xg[rowx + 512 + d] = hi;
          p.xg[rowx + 1536 + d] = lo;
          p.xg[rowx + 2560 + d] = hi;
          p.dox[rowd + d] = hi;
          p.dox[rowd + 544 + d] = lo;
          p.dox[rowd + 1088 + d] = hi;
        }
        if (lane < 32) {
          float ov = (lane < 18) ? p.obs[((size_t)b * TT + t) * 18 + lane] : 0.f;
          u16 hi = f2b(ov); u16 lo = f2b(ov - b2f(hi));
          p.dox[rowd + 512 + lane] = hi;
          p.dox[rowd + 1056 + lane] = lo;
          p.dox[rowd + 1600 + lane] = hi;
        }
      }
      grid.sync();

      // ---- D: hraw = dox3 @ W2T3  (Sk x 1024, K3=1632) ----
      gemm_tiles(p.dox, 1632, p.W2T3, 1632, p.hraw, 1024, Sk, 8, 1632,
                 lds, bid, nb, tid);
      grid.sync();

      // ---- E: two LNs + silu -> h2 planes ----
      for (int i = gw; i < Sk; i += nwv) {
        size_t rowh = (size_t)i * 3072;
        #pragma unroll
        for (int hh = 0; hh < 2; ++hh) {
          const float* hb = p.hraw + (size_t)i * 1024 + (hh << 9);
          const float* gv = hh ? p.g_post : p.g_prior_out;
          const float* bv = hh ? p.bb_post : p.bb_prior_out;
          float v[8];
          float sm = 0.f, sq = 0.f;
          #pragma unroll
          for (int c = 0; c < 8; ++c) {
            v[c] = hb[lane + (c << 6)];
            sm += v[c]; sq += v[c] * v[c];
          }
          #pragma unroll
          for (int o = 32; o; o >>= 1) { sm += __shfl_xor(sm, o); sq += __shfl_xor(sq, o); }
          float m = sm * (1.f / 512.f);
          float rs = rsqrtf(sq * (1.f / 512.f) - m * m + 1e-3f);
          #pragma unroll
          for (int c = 0; c < 8; ++c) {
            int d = lane + (c << 6);
            float x = (v[c] - m) * rs * gv[d] + bv[d];
            x = x * sigm(x);
            int col = (hh << 9) + d;
            u16 hi = f2b(x); u16 lo = f2b(x - b2f(hi));
            p.h2[rowh + col] = hi;
            p.h2[rowh + 1024 + col] = lo;
            p.h2[rowh + 2048 + col] = hi;
          }
        }
      }
      grid.sync();

      // ---- F: stats = h2 @ WsT3 (32-row tiles, N=128, K3=3072, dbuf) + epilogue ----
      // LDS: FA buf0 [0,1024) buf1 [1024,2048); FB buf0 [2048,6144) buf1 [6144,10240)
      {
        const int sr = (wave & 1) << 4, sc = (wave >> 1) << 6;
        const int frow = tid >> 2, fko = (tid & 3) << 3;
        int njobs = (Sk + 31) >> 5;
        const u16* gbF0 = p.WsT3 + (size_t)frow * 3072 + fko;
        const u16* gbF1 = p.WsT3 + (size_t)(frow + 64) * 3072 + fko;
        u16* const lFA = lds + (wave << 9);          // waves 0,1 only
        u16* const lFB0 = lds + 2048 + (wave << 9);
        u16* const lFB1 = lds + 2048 + 2048 + (wave << 9);
        for (int j = bid; j < njobs; j += nb) {
          int r0 = j << 5;
          const u16* gaF = p.h2 + (size_t)(r0 + frow) * 3072 + fko;
          f32x4 acc[4];
          #pragma unroll
          for (int z = 0; z < 4; ++z) acc[z] = f32x4{0.f, 0.f, 0.f, 0.f};
          __syncthreads();
          if (tid < 128) GLL(gaF, lFA);
          GLL(gbF0, lFB0); GLL(gbF1, lFB1);
          int buf = 0;
          for (int k0 = 0; k0 < 3072; k0 += 32) {
            __syncthreads();
            if (k0 + 32 < 3072) {
              int nbuf = buf ^ 1;
              int o = k0 + 32;
              if (tid < 128) GLL(gaF + o, lFA + (nbuf << 10));
              GLL(gbF0 + o, lFB0 + (nbuf << 12));
              GLL(gbF1 + o, lFB1 + (nbuf << 12));
            }
            const u16* FA = lds + (buf << 10);
            const u16* FB = lds + 2048 + (buf << 12);
            bf16x8 af = *(const bf16x8*)&FA[((sr + l15) << 5) + (quad << 3)];
            #pragma unroll
            for (int ns = 0; ns < 4; ++ns) {
              bf16x8 bf = *(const bf16x8*)&FB[((sc + (ns << 4) + l15) << 5) + (quad << 3)];
              acc[ns] = __builtin_amdgcn_mfma_f32_16x16x32_bf16(af, bf, acc[ns], 0, 0, 0);
            }
            buf ^= 1;
          }
          #pragma unroll
          for (int ns = 0; ns < 4; ++ns)
            #pragma unroll
            for (int r = 0; r < 4; ++r) {
              int i = r0 + sr + (quad << 2) + r;
              int col = sc + (ns << 4) + l15;
              if (i < Sk) {
                float v = acc[ns][r];
                int gi = base + i;
                int b = p.segb[gi], t = p.segt0[gi] + k;
                float* orow = p.out + ((size_t)b * TT + t) * 1216;
                if (col < 32) {
                  v += p.b_prior_stats[col];
                  orow[1120 + col] = v; orow[1152 + col] = v;
                } else if (col < 64) {
                  v = splus(v + p.b_prior_stats[col]) + 0.1f;
                  orow[1184 + col - 32] = v;
                } else if (col < 96) {
                  v += p.b_post_stats[col - 64];
                  orow[512 + col - 64] = v; orow[544 + col - 64] = v;
                  p.stoch[(size_t)i * 32 + (col - 64)] = v;
                } else {
                  v = splus(v + p.b_post_stats[col - 64]) + 0.1f;
                  orow[576 + col - 96] = v;
                }
              }
            }
        }
      }
      grid.sync();
    }
  }
}

extern "C" void kernel_launch(void* const* d_in, const int* in_sizes, int n_in,
                              void* d_out, int out_size, void* d_ws, size_t ws_size,
                              hipStream_t stream) {
  P p;
  p.obs = (const float*)d_in[0];
  p.action = (const float*)d_in[1];
  p.is_first = (const int*)d_in[2];
  p.w_prior_in = (const float*)d_in[3];
  p.g_prior_in = (const float*)d_in[4];
  p.bb_prior_in = (const float*)d_in[5];
  p.w_gru = (const float*)d_in[6];
  p.g_gru = (const float*)d_in[7];
  p.bb_gru = (const float*)d_in[8];
  p.w_prior_out = (const float*)d_in[9];
  p.g_prior_out = (const float*)d_in[10];
  p.bb_prior_out = (const float*)d_in[11];
  p.w_prior_stats = (const float*)d_in[12];
  p.b_prior_stats = (const float*)d_in[13];
  p.w_post = (const float*)d_in[14];
  p.g_post = (const float*)d_in[15];
  p.bb_post = (const float*)d_in[16];
  p.w_post_stats = (const float*)d_in[17];
  p.b_post_stats = (const float*)d_in[18];
  p.initial_deter = (const float*)d_in[19];
  p.out = (float*)d_out;

  char* w = (char*)d_ws;
  auto alloc = [&](size_t bytes) -> char* {
    char* r = w; w += (bytes + 255) & ~(size_t)255; return r;
  };
  p.WgT3 = (u16*)alloc((size_t)1536 * 3072 * 2);
  p.W2T3 = (u16*)alloc((size_t)1024 * 1632 * 2);
  p.WsT3 = (u16*)alloc((size_t)128 * 3072 * 2);
  p.deter0    = (float*)alloc(512 * 4);
  p.init_mean = (float*)alloc(32 * 4);
  p.segb  = (int*)alloc((size_t)65536 * 4);
  p.segt0 = (int*)alloc((size_t)65536 * 4);
  p.nact  = (int*)alloc(257 * 4);
  size_t used = (size_t)(w - (char*)d_ws);
  size_t avail = ws_size > used ? ws_size - used : 0;
  // per-row: deter 2048 + stoch 128 + xg 6144 + gates 6144 + dox 3264 + hraw 4096 + h2 6144 = 27968 B
  long long ch = (long long)(avail / 28672);
  if (ch > 8192) ch = 8192;
  ch &= ~127LL;
  if (ch < 128) ch = 128;
  p.CH = (int)ch;
  p.deter = (float*)alloc((size_t)p.CH * 512 * 4);
  p.stoch = (float*)alloc((size_t)p.CH * 32 * 4);
  p.xg    = (u16*)alloc((size_t)p.CH * 3072 * 2);
  p.gates = (float*)alloc((size_t)p.CH * 1536 * 4);
  p.dox   = (u16*)alloc((size_t)p.CH * 1632 * 2);
  p.hraw  = (float*)alloc((size_t)p.CH * 1024 * 4);
  p.h2    = (u16*)alloc((size_t)p.CH * 3072 * 2);

  k_weights<<<dim3(256), dim3(256), 0, stream>>>(p);
  k_init_state<<<dim3(1), dim3(256), 0, stream>>>(p);
  k_segments<<<dim3(1), dim3(256), 0, stream>>>(p);
  void* args[] = { &p };
  hipLaunchCooperativeKernel(reinterpret_cast<void*>(&k_main), dim3(GRID), dim3(BDIM),
                             args, 0, stream);
}